// Round 10
// baseline (339.348 us; speedup 1.0000x reference)
//
#include <hip/hip_runtime.h>
#include <hip/hip_fp16.h>

typedef _Float16 f16;
typedef _Float16 f16x8 __attribute__((ext_vector_type(8)));
typedef _Float16 f16x4 __attribute__((ext_vector_type(4)));
typedef float    f32x4 __attribute__((ext_vector_type(4)));
typedef float    f32x16 __attribute__((ext_vector_type(16)));

// B=2, S=2048, H=1024, NH=16, D=64 hard-coded throughout.
#define BAR_LDS() asm volatile("s_waitcnt lgkmcnt(0)\n\ts_barrier" ::: "memory")

// ---------------- fp32 -> f16 convert (3 tensors batched via blockIdx.y) ----
__global__ __launch_bounds__(256) void cvt3(const float* __restrict__ a,
                                            const float* __restrict__ b,
                                            const float* __restrict__ c,
                                            f16* __restrict__ out, int per) {
  const float* src = blockIdx.y == 0 ? a : (blockIdx.y == 1 ? b : c);
  int i = (blockIdx.x * 256 + threadIdx.x) * 4;
  if (i >= per) return;
  f32x4 v = *(const f32x4*)(src + i);
  f16x4 h; h[0]=(f16)v[0]; h[1]=(f16)v[1]; h[2]=(f16)v[2]; h[3]=(f16)v[3];
  *(f16x4*)(out + (size_t)blockIdx.y * per + i) = h;
}

// ---------------- mask -> transposed bit matrix -----------------------------
// mT[b][qw (64)][key (2048)]: dword holds bits for q-rows qw*32..+31 at key.
__global__ __launch_bounds__(256) void pack_maskT(const int* __restrict__ m,
                                                  unsigned* __restrict__ mT) {
  const int b = blockIdx.z, qw = blockIdx.y;
  const int key = blockIdx.x * 256 + threadIdx.x;
  const int* base = m + (((size_t)b * 2048 + qw * 32) << 11) + key;
  unsigned acc = 0;
#pragma unroll
  for (int q = 0; q < 32; q++) acc |= (base[(size_t)q << 11] != 0 ? 1u : 0u) << q;
  mT[(((size_t)b * 64 + qw) << 11) + key] = acc;
}

// ---------------- async global->LDS helper ----------------------------------
__device__ inline void gld16(const void* g, void* l) {
  __builtin_amdgcn_global_load_lds((const __attribute__((address_space(1))) void*)g,
                                   (__attribute__((address_space(3))) void*)l, 16, 0, 0);
}

// ---------------- projection GEMM: Y = X @ W^T ------------------------------
__global__ __launch_bounds__(256) void gemm_proj(const f16* __restrict__ Xall,
                                                 const f16* __restrict__ Wall,
                                                 f16* __restrict__ Qh,
                                                 f16* __restrict__ Kh,
                                                 f16* __restrict__ Vn) {
  __shared__ f16 lA[4][128][8];   // [kslot][row][8]
  __shared__ f16 lB[4][128][8];
  const int z = blockIdx.z;
  const f16* A  = Xall + (size_t)z * (4096u * 1024u);
  const f16* Wt = Wall + (size_t)z * (1024u * 1024u);
  f16* Y = (z == 0) ? Qh : (z == 1 ? Kh : Vn);
  const int t = threadIdx.x;
  const int brow = blockIdx.y * 128, bcol = blockIdx.x * 128;
  const int w = t >> 6, l = t & 63;
  const int wr = w >> 1, wc = w & 1;
  const int lr = l & 15, lg = l >> 4;
  f32x4 acc[4][4] = {};

  for (int k0 = 0; k0 < 1024; k0 += 32) {
#pragma unroll
    for (int j = 0; j < 2; j++) {
      const int p = j * 4096 + t * 16;
      const int ks = p >> 11, row = (p >> 4) & 127;
      gld16(A  + (size_t)(brow + row) * 1024 + k0 + ks * 8, (char*)lA + p);
      gld16(Wt + (size_t)(bcol + row) * 1024 + k0 + ks * 8, (char*)lB + p);
    }
    __syncthreads();
    f16x8 af[4], bf[4];
#pragma unroll
    for (int mi = 0; mi < 4; mi++) af[mi] = *(const f16x8*)&lA[lg][wr * 64 + mi * 16 + lr][0];
#pragma unroll
    for (int ni = 0; ni < 4; ni++) bf[ni] = *(const f16x8*)&lB[lg][wc * 64 + ni * 16 + lr][0];
#pragma unroll
    for (int mi = 0; mi < 4; mi++)
#pragma unroll
      for (int ni = 0; ni < 4; ni++)
        acc[mi][ni] = __builtin_amdgcn_mfma_f32_16x16x32_f16(af[mi], bf[ni], acc[mi][ni], 0, 0, 0);
    __syncthreads();
  }

  const int mb0 = brow + wr * 64, nb0 = bcol + wc * 64;
#pragma unroll
  for (int mi = 0; mi < 4; mi++)
#pragma unroll
    for (int ni = 0; ni < 4; ni++)
#pragma unroll
      for (int j = 0; j < 4; j++) {
        const int m = mb0 + mi * 16 + lg * 4 + j;
        const int n = nb0 + ni * 16 + lr;
        const int bb = m >> 11, s = m & 2047;
        const int h = n >> 6, d = n & 63;
        Y[((((size_t)bb * 16 + h) * 2048 + s) << 6) + d] = (f16)acc[mi][ni][j];
      }
}

// ---------------- V transpose: [bh][s][64] -> [bh][d][2048] -----------------
__global__ __launch_bounds__(512) void transposeV(const f16* __restrict__ Vn,
                                                  f16* __restrict__ VhT) {
  const int bh = blockIdx.y, s0 = blockIdx.x * 64;
  const int t = threadIdx.x, l = t & 63, w = t >> 6;
  const f16x8 v = *(const f16x8*)(Vn + (((size_t)bh * 2048 + s0 + l) << 6) + w * 8);
#pragma unroll
  for (int e = 0; e < 8; e++)
    VhT[(((size_t)bh * 64 + w * 8 + e) << 11) + s0 + l] = v[e];
}

// ====================== 32x32 MFMA attention kernels ========================
// mfma_f32_32x32x16_f16: A/B frag lane holds row/col = lane&31, k = 8*(lane>>5)+e.
// C/D: col = lane&31, row = (reg&3) + 8*(reg>>2) + 4*(lane>>5).
// K tile LDS: [128 rows][128 B], XOR swizzle byte ^= (row&7)<<4.
// P tile per wave: [32 rows][128 f16] (256 B stride), SAME XOR swizzle
// (32 lanes at 256-B stride would be a full bank collision otherwise).

__device__ inline int kswz(int p) {           // staging: flat p -> swizzled
  return (p & ~127) | ((p & 127) ^ (((p >> 7) & 7) << 4));
}

// ---------------- kernel A: exp-sum pass (32x32) ----------------------------
__global__ __launch_bounds__(256, 4) void sumexp_k(const f16* __restrict__ Qh,
                                                   const f16* __restrict__ Kh,
                                                   const unsigned* __restrict__ mT,
                                                   float* __restrict__ SIo) {
  __shared__ char lK[16384];        // 16 KB, swizzled rows of 128 B
  const int wg = blockIdx.x;
  const int bh = ((wg & 7) << 2) | (wg >> 7);
  const int qg = (wg >> 3) & 15;
  const int b = bh >> 4;
  const int t = threadIdx.x, w = t >> 6, l = t & 63;
  const int l5 = l & 31, hi = l >> 5;
  const int qr = qg * 128 + w * 32;

  const char* Kbase = (const char*)(Kh + ((size_t)bh << 17));
  const char* qpb = (const char*)Qh + (((size_t)bh * 2048 + qr + l5) << 7) + 16 * hi;
  f16x8 aq[4];
#pragma unroll
  for (int kk = 0; kk < 4; kk++) aq[kk] = *(const f16x8*)(qpb + 32 * kk);
  const unsigned* mTb = mT + (((size_t)(b * 64 + (qr >> 5))) << 11);

  float sums[16] = {};
  f16x8 kpre[4];
#pragma unroll
  for (int j = 0; j < 4; j++)
    kpre[j] = *(const f16x8*)(Kbase + (size_t)(t * 16 + j * 4096));

  for (int t16 = 0; t16 < 16; t16++) {
    const int kb = t16 * 128;
    BAR_LDS();
#pragma unroll
    for (int j = 0; j < 4; j++) *(f16x8*)(lK + kswz(t * 16 + j * 4096)) = kpre[j];
    BAR_LDS();
    unsigned mw[4];
#pragma unroll
    for (int blk = 0; blk < 4; blk++) mw[blk] = mTb[kb + blk * 32 + l5];
    if (t16 < 15) {
      const char* nb = Kbase + (((size_t)kb + 128) << 7);
#pragma unroll
      for (int j = 0; j < 4; j++) kpre[j] = *(const f16x8*)(nb + (size_t)(t * 16 + j * 4096));
    }
#pragma unroll
    for (int blk = 0; blk < 4; blk++) {
      f32x16 acc = {};
#pragma unroll
      for (int kk = 0; kk < 4; kk++) {
        const int row = blk * 32 + l5;
        const f16x8 bk = *(const f16x8*)(lK + (row << 7) + ((32 * kk + 16 * hi) ^ ((l5 & 7) << 4)));
        acc = __builtin_amdgcn_mfma_f32_32x32x16_f16(aq[kk], bk, acc, 0, 0, 0);
      }
#pragma unroll
      for (int r = 0; r < 16; r++) {
        const int rq = (r & 3) + 8 * (r >> 2) + 4 * hi;
        sums[r] += ((mw[blk] >> rq) & 1u) ? __expf(acc[r]) : 0.f;
      }
    }
  }
#pragma unroll
  for (int r = 0; r < 16; r++) {
#pragma unroll
    for (int o = 1; o < 32; o <<= 1) sums[r] += __shfl_xor(sums[r], o, 64);
  }
  if (l5 == 0) {
    float* o = SIo + ((size_t)bh << 11) + qr;
#pragma unroll
    for (int r = 0; r < 16; r++) {
      const int rq = (r & 3) + 8 * (r >> 2) + 4 * hi;
      o[rq] = 1.0f / sums[r];
    }
  }
}

// ---------------- kernel B: normalize + attn store + PV (32x32) -------------
__global__ __launch_bounds__(256, 2) void attn_pv(const f16* __restrict__ Qh,
                                                  const f16* __restrict__ Kh,
                                                  const f16* __restrict__ VhT,
                                                  const unsigned* __restrict__ mT,
                                                  const float* __restrict__ SIo,
                                                  float* __restrict__ attn,
                                                  float* __restrict__ ctx) {
  __shared__ char lK[16384];        // swizzled K tile [128 rows][128 B]
  __shared__ f16 lVT[16][64][8];    // 16 KB: [k/8][d][8]
  __shared__ char Pw[4][8192];      // per-wave P: [32 rows][128 f16], swizzled
  const int wg = blockIdx.x;
  const int bh = ((wg & 7) << 2) | (wg >> 7);
  const int qg = (wg >> 3) & 15;
  const int b = bh >> 4, h = bh & 15;
  const int t = threadIdx.x, w = t >> 6, l = t & 63;
  const int l5 = l & 31, hi = l >> 5;
  const int qr = qg * 128 + w * 32;
  char* wb = Pw[w];

  const char* Kbase = (const char*)(Kh + ((size_t)bh << 17));
  const char* Vbase = (const char*)(VhT + ((size_t)bh << 17));
  const char* qpb = (const char*)Qh + (((size_t)bh * 2048 + qr + l5) << 7) + 16 * hi;
  f16x8 aq[4];
#pragma unroll
  for (int kk = 0; kk < 4; kk++) aq[kk] = *(const f16x8*)(qpb + 32 * kk);
  const unsigned* mTb = mT + (((size_t)(b * 64 + (qr >> 5))) << 11);

  float SIv[16];
  {
    const float* sb = SIo + ((size_t)bh << 11) + qr;
#pragma unroll
    for (int r = 0; r < 16; r++) SIv[r] = sb[(r & 3) + 8 * (r >> 2) + 4 * hi];
  }

  f32x16 acc2[2] = {};
  f16x8 kpre[4], vpre[4];
#pragma unroll
  for (int j = 0; j < 4; j++) {
    const int p = t * 16 + j * 4096;
    kpre[j] = *(const f16x8*)(Kbase + (size_t)p);
    vpre[j] = *(const f16x8*)(Vbase + (((size_t)((p >> 4) & 63)) << 12) + ((p >> 10) << 4));
  }
  float* abase = attn + (((size_t)bh * 2048 + qr) << 11);
  const int srow8 = l >> 3, scol = (l & 7) * 4;

  for (int t16 = 0; t16 < 16; t16++) {
    const int kb = t16 * 128;
    BAR_LDS();
#pragma unroll
    for (int j = 0; j < 4; j++) {
      const int p = t * 16 + j * 4096;
      *(f16x8*)(lK + kswz(p)) = kpre[j];
      *(f16x8*)((char*)lVT + p) = vpre[j];
    }
    BAR_LDS();
    unsigned mw[4];
#pragma unroll
    for (int blk = 0; blk < 4; blk++) mw[blk] = mTb[kb + blk * 32 + l5];
    if (t16 < 15) {
      const char* nk = Kbase + (((size_t)kb + 128) << 7);
      const char* nv = Vbase + (((size_t)kb + 128) << 1);
#pragma unroll
      for (int j = 0; j < 4; j++) {
        const int p = t * 16 + j * 4096;
        kpre[j] = *(const f16x8*)(nk + (size_t)p);
        vpre[j] = *(const f16x8*)(nv + (((size_t)((p >> 4) & 63)) << 12) + ((p >> 10) << 4));
      }
    }
    // QK per 32-key block -> exp -> P (f16) to wave-private swizzled LDS
#pragma unroll
    for (int blk = 0; blk < 4; blk++) {
      f32x16 acc = {};
#pragma unroll
      for (int kk = 0; kk < 4; kk++) {
        const int row = blk * 32 + l5;
        const f16x8 bk = *(const f16x8*)(lK + (row << 7) + ((32 * kk + 16 * hi) ^ ((l5 & 7) << 4)));
        acc = __builtin_amdgcn_mfma_f32_32x32x16_f16(aq[kk], bk, acc, 0, 0, 0);
      }
#pragma unroll
      for (int r = 0; r < 16; r++) {
        const int rq = (r & 3) + 8 * (r >> 2) + 4 * hi;
        const float pj = ((mw[blk] >> rq) & 1u) ? __expf(acc[r]) * SIv[r] : 0.f;
        *(f16*)(wb + rq * 256 + (((blk * 32 + l5) * 2) ^ ((rq & 7) << 4))) = (f16)pj;
      }
    }
    // PV: A = P (wave-private, swizzled read), B = V^T tile
#pragma unroll
    for (int ks = 0; ks < 8; ks++) {
      const f16x8 pa = *(const f16x8*)(wb + l5 * 256 + ((32 * ks + 16 * hi) ^ ((l5 & 7) << 4)));
#pragma unroll
      for (int db = 0; db < 2; db++) {
        const f16x8 bv = *(const f16x8*)((char*)lVT + ((2 * ks + hi) << 10) + ((db * 32 + l5) << 4));
        acc2[db] = __builtin_amdgcn_mfma_f32_32x32x16_f16(pa, bv, acc2[db], 0, 0, 0);
      }
    }
    // attn stores: readback P, f32x4; 8 lanes span 128 B of one row.
#pragma unroll
    for (int h2 = 0; h2 < 4; h2++) {
      const int row = srow8 + h2 * 8;
      float* arow = abase + ((size_t)row << 11) + kb + scol;
#pragma unroll
      for (int u = 0; u < 4; u++) {
        const f16x4 p4 = *(const f16x4*)(wb + row * 256 + (((scol + 32 * u) * 2) ^ ((row & 7) << 4)));
        f32x4 o;
#pragma unroll
        for (int e = 0; e < 4; e++) o[e] = (float)p4[e];
        *(f32x4*)(arow + u * 32) = o;
      }
    }
  }

  // ctx write: rows qr+rq, cols h*64 + db*32 + l5
#pragma unroll
  for (int db = 0; db < 2; db++)
#pragma unroll
    for (int r = 0; r < 16; r++) {
      const int rq = (r & 3) + 8 * (r >> 2) + 4 * hi;
      ctx[((size_t)b * 2048 + qr + rq) * 1024 + h * 64 + db * 32 + l5] = acc2[db][r];
    }
}

// ---------------- residual + LayerNorm (in place on d_out) ------------------
__global__ __launch_bounds__(256) void ln_res(const float* __restrict__ qres,
                                              const float* __restrict__ gamma,
                                              const float* __restrict__ beta,
                                              float* __restrict__ io) {
  const int tok = blockIdx.x;
  const int t = threadIdx.x;
  float* rowp = io + (size_t)tok * 1024;
  const float* qp = qres + (size_t)tok * 1024;
  const f32x4 c = *(const f32x4*)(rowp + t * 4);
  const f32x4 r = *(const f32x4*)(qp + t * 4);
  f32x4 vals;
  float s = 0.f, s2 = 0.f;
#pragma unroll
  for (int e = 0; e < 4; e++) { float x = c[e] + r[e]; vals[e] = x; s += x; s2 += x * x; }
#pragma unroll
  for (int o = 1; o < 64; o <<= 1) { s += __shfl_xor(s, o, 64); s2 += __shfl_xor(s2, o, 64); }
  __shared__ float rs[4][2];
  const int w = t >> 6;
  if ((t & 63) == 0) { rs[w][0] = s; rs[w][1] = s2; }
  __syncthreads();
  s  = rs[0][0] + rs[1][0] + rs[2][0] + rs[3][0];
  s2 = rs[0][1] + rs[1][1] + rs[2][1] + rs[3][1];
  const float mu = s * (1.f / 1024.f);
  const float var = s2 * (1.f / 1024.f) - mu * mu;
  const float rstd = rsqrtf(var + 1e-6f);
  const f32x4 g  = *(const f32x4*)(gamma + t * 4);
  const f32x4 be = *(const f32x4*)(beta + t * 4);
  f32x4 o;
#pragma unroll
  for (int e = 0; e < 4; e++) o[e] = (vals[e] - mu) * rstd * g[e] + be[e];
  *(f32x4*)(rowp + t * 4) = o;
}

// ---------------- host ------------------------------------------------------
extern "C" void kernel_launch(void* const* d_in, const int* in_sizes, int n_in,
                              void* d_out, int out_size, void* d_ws, size_t ws_size,
                              hipStream_t stream) {
  const float* q     = (const float*)d_in[0];
  const float* k     = (const float*)d_in[1];
  const float* v     = (const float*)d_in[2];
  const int*   mask  = (const int*)d_in[3];
  const float* Wq    = (const float*)d_in[4];
  const float* Wk    = (const float*)d_in[5];
  const float* Wv    = (const float*)d_in[6];
  const float* gamma = (const float*)d_in[7];
  const float* beta  = (const float*)d_in[8];
  float* out  = (float*)d_out;
  float* attn = out + (size_t)4194304;       // B*S*H
  const size_t MB = 1u << 20;
  char* ws = (char*)d_ws;

  f16 *x16, *W16, *Qh, *Kh, *Vn, *VhT; unsigned* mb; float* SIo;
  if (ws_size >= 65 * MB) {
    x16 = (f16*)ws;              W16 = (f16*)(ws + 24 * MB);
    Qh  = (f16*)(ws + 30 * MB);  Kh  = (f16*)(ws + 38 * MB);
    Vn  = (f16*)(ws + 46 * MB);  VhT = (f16*)(ws + 54 * MB);
    mb  = (unsigned*)(ws + 62 * MB);
    SIo = (float*)(ws + 63 * MB);
  } else {
    x16 = (f16*)attn;            W16 = (f16*)((char*)attn + 24 * MB);
    Vn  = (f16*)((char*)attn + 30 * MB);
    Qh  = (f16*)ws;              Kh  = (f16*)(ws + 8 * MB);
    VhT = (f16*)(ws + 16 * MB);  mb  = (unsigned*)(ws + 24 * MB);
    SIo = (float*)(ws + 25 * MB);
  }

  cvt3<<<dim3(4096, 3), 256, 0, stream>>>(q, k, v, x16, 4194304);
  cvt3<<<dim3(1024, 3), 256, 0, stream>>>(Wq, Wk, Wv, W16, 1048576);
  pack_maskT<<<dim3(8, 64, 2), 256, 0, stream>>>(mask, mb);
  gemm_proj<<<dim3(8, 32, 3), 256, 0, stream>>>(x16, W16, Qh, Kh, Vn);
  transposeV<<<dim3(32, 32), 512, 0, stream>>>(Vn, VhT);
  sumexp_k<<<dim3(512), 256, 0, stream>>>(Qh, Kh, mb, SIo);
  attn_pv<<<dim3(512), 256, 0, stream>>>(Qh, Kh, VhT, mb, SIo, attn, out);
  ln_res<<<dim3(4096), 256, 0, stream>>>(q, gamma, beta, out);
}

// Round 11
// 333.722 us; speedup vs baseline: 1.0169x; 1.0169x over previous
//
#include <hip/hip_runtime.h>
#include <hip/hip_fp16.h>

typedef _Float16 f16;
typedef _Float16 f16x8 __attribute__((ext_vector_type(8)));
typedef _Float16 f16x4 __attribute__((ext_vector_type(4)));
typedef float    f32x4 __attribute__((ext_vector_type(4)));

// B=2, S=2048, H=1024, NH=16, D=64 hard-coded throughout.
#define BAR_LDS() asm volatile("s_waitcnt lgkmcnt(0)\n\ts_barrier" ::: "memory")

// ---------------- fp32 -> f16 convert (3 tensors batched via blockIdx.y) ----
__global__ __launch_bounds__(256) void cvt3(const float* __restrict__ a,
                                            const float* __restrict__ b,
                                            const float* __restrict__ c,
                                            f16* __restrict__ out, int per) {
  const float* src = blockIdx.y == 0 ? a : (blockIdx.y == 1 ? b : c);
  int i = (blockIdx.x * 256 + threadIdx.x) * 4;
  if (i >= per) return;
  f32x4 v = *(const f32x4*)(src + i);
  f16x4 h; h[0]=(f16)v[0]; h[1]=(f16)v[1]; h[2]=(f16)v[2]; h[3]=(f16)v[3];
  *(f16x4*)(out + (size_t)blockIdx.y * per + i) = h;
}

// ---------------- mask int32 -> bitmask (1 bit per entry) -------------------
__global__ __launch_bounds__(256) void pack_mask(const int* __restrict__ m,
                                                 unsigned* __restrict__ bits) {
  size_t i = (size_t)blockIdx.x * 256 + threadIdx.x;
  unsigned long long b = __ballot(m[i] != 0);
  int lane = threadIdx.x & 63;
  if (lane == 0)       bits[i >> 5] = (unsigned)b;
  else if (lane == 32) bits[i >> 5] = (unsigned)(b >> 32);
}

// ---------------- async global->LDS helper ----------------------------------
__device__ inline void gld16(const void* g, void* l) {
  __builtin_amdgcn_global_load_lds((const __attribute__((address_space(1))) void*)g,
                                   (__attribute__((address_space(3))) void*)l, 16, 0, 0);
}

// ---------------- projection GEMM: Y = X @ W^T ------------------------------
__global__ __launch_bounds__(256) void gemm_proj(const f16* __restrict__ Xall,
                                                 const f16* __restrict__ Wall,
                                                 f16* __restrict__ Qh,
                                                 f16* __restrict__ Kh,
                                                 f16* __restrict__ Vn) {
  __shared__ f16 lA[4][128][8];   // [kslot][row][8]
  __shared__ f16 lB[4][128][8];
  const int z = blockIdx.z;
  const f16* A  = Xall + (size_t)z * (4096u * 1024u);
  const f16* Wt = Wall + (size_t)z * (1024u * 1024u);
  f16* Y = (z == 0) ? Qh : (z == 1 ? Kh : Vn);
  const int t = threadIdx.x;
  const int brow = blockIdx.y * 128, bcol = blockIdx.x * 128;
  const int w = t >> 6, l = t & 63;
  const int wr = w >> 1, wc = w & 1;
  const int lr = l & 15, lg = l >> 4;
  f32x4 acc[4][4] = {};

  for (int k0 = 0; k0 < 1024; k0 += 32) {
#pragma unroll
    for (int j = 0; j < 2; j++) {
      const int p = j * 4096 + t * 16;
      const int ks = p >> 11, row = (p >> 4) & 127;
      gld16(A  + (size_t)(brow + row) * 1024 + k0 + ks * 8, (char*)lA + p);
      gld16(Wt + (size_t)(bcol + row) * 1024 + k0 + ks * 8, (char*)lB + p);
    }
    __syncthreads();
    f16x8 af[4], bf[4];
#pragma unroll
    for (int mi = 0; mi < 4; mi++) af[mi] = *(const f16x8*)&lA[lg][wr * 64 + mi * 16 + lr][0];
#pragma unroll
    for (int ni = 0; ni < 4; ni++) bf[ni] = *(const f16x8*)&lB[lg][wc * 64 + ni * 16 + lr][0];
#pragma unroll
    for (int mi = 0; mi < 4; mi++)
#pragma unroll
      for (int ni = 0; ni < 4; ni++)
        acc[mi][ni] = __builtin_amdgcn_mfma_f32_16x16x32_f16(af[mi], bf[ni], acc[mi][ni], 0, 0, 0);
    __syncthreads();
  }

  const int mb0 = brow + wr * 64, nb0 = bcol + wc * 64;
#pragma unroll
  for (int mi = 0; mi < 4; mi++)
#pragma unroll
    for (int ni = 0; ni < 4; ni++)
#pragma unroll
      for (int j = 0; j < 4; j++) {
        const int m = mb0 + mi * 16 + lg * 4 + j;
        const int n = nb0 + ni * 16 + lr;
        const int bb = m >> 11, s = m & 2047;
        const int h = n >> 6, d = n & 63;
        Y[((((size_t)bb * 16 + h) * 2048 + s) << 6) + d] = (f16)acc[mi][ni][j];
      }
}

// ---------------- V transpose: [bh][s][64] -> [bh][d][2048] -----------------
__global__ __launch_bounds__(512) void transposeV(const f16* __restrict__ Vn,
                                                  f16* __restrict__ VhT) {
  const int bh = blockIdx.y, s0 = blockIdx.x * 64;
  const int t = threadIdx.x, l = t & 63, w = t >> 6;
  const f16x8 v = *(const f16x8*)(Vn + (((size_t)bh * 2048 + s0 + l) << 6) + w * 8);
#pragma unroll
  for (int e = 0; e < 8; e++)
    VhT[(((size_t)bh * 64 + w * 8 + e) << 11) + s0 + l] = v[e];
}

// ============== swapped-QK attention (mfma(K,Q)): lane owns one q-row =======
// mfma_f32_16x16x32_f16 fragments are A/B symmetric (row/col = lane&15,
// k = 8*(lane>>4)+e), so swapping operands reuses identical LDS reads.
// D with A=K, B=Q: col = q = lane&15, row = key = 4*(lane>>4)+j -> each lane
// holds 4 CONSECUTIVE keys of one q-row: direct f32x4 attn stores + f16x4
// vectorized P writes, one mask uint4 per lane per tile.

// ---------------- kernel A: exp-sum pass ------------------------------------
__global__ __launch_bounds__(512, 6) void sumexp_k(const f16* __restrict__ Qh,
                                                   const f16* __restrict__ Kh,
                                                   const unsigned* __restrict__ mbits,
                                                   float* __restrict__ SIo) {
  __shared__ f16 lK[8][128][8];     // 16 KB
  const int wg = blockIdx.x;
  const int bh = ((wg & 7) << 2) | (wg >> 7);    // 16 blocks/bh on ONE XCD
  const int qg = (wg >> 3) & 15;
  const int b = bh >> 4;
  const int t = threadIdx.x, w = t >> 6, l = t & 63;
  const int lr = l & 15, lg = l >> 4;
  const int qr = qg * 128 + w * 16;

  const int pA = t * 16, pB = 8192 + t * 16;
  const int ksA = pA >> 11, rwA = (pA >> 4) & 127;
  const int ksB = pB >> 11, rwB = (pB >> 4) & 127;
  const f16* Kbase = Kh + ((size_t)bh << 17);

  const f16* qp = Qh + (((size_t)bh * 2048 + qr + lr) << 6) + lg * 8;
  const f16x8 aq0 = *(const f16x8*)qp;
  const f16x8 aq1 = *(const f16x8*)(qp + 32);
  const unsigned* mrow = mbits + ((size_t)b * 2048 + qr + lr) * 64;

  float sum = 0.f;
  f16x8 kra = *(const f16x8*)(Kbase + ((size_t)rwA << 6) + ksA * 8);
  f16x8 krb = *(const f16x8*)(Kbase + ((size_t)rwB << 6) + ksB * 8);
  for (int t16 = 0; t16 < 16; t16++) {
    const int kb = t16 * 128;
    BAR_LDS();
    *(f16x8*)((char*)lK + pA) = kra;
    *(f16x8*)((char*)lK + pB) = krb;
    BAR_LDS();
    const uint4 mw4 = *(const uint4*)(mrow + (kb >> 5));
    const unsigned mwv[4] = {mw4.x, mw4.y, mw4.z, mw4.w};
    if (t16 < 15) {
      const f16* nb = Kbase + ((size_t)(kb + 128) << 6);
      kra = *(const f16x8*)(nb + ((size_t)rwA << 6) + ksA * 8);
      krb = *(const f16x8*)(nb + ((size_t)rwB << 6) + ksB * 8);
    }
#pragma unroll
    for (int nf = 0; nf < 8; nf++) {
      f32x4 s4 = {};
      s4 = __builtin_amdgcn_mfma_f32_16x16x32_f16(*(const f16x8*)&lK[lg][nf * 16 + lr][0], aq0, s4, 0, 0, 0);
      s4 = __builtin_amdgcn_mfma_f32_16x16x32_f16(*(const f16x8*)&lK[4 + lg][nf * 16 + lr][0], aq1, s4, 0, 0, 0);
      const unsigned word = mwv[nf >> 1];
      const unsigned bp = ((nf & 1) << 4) + lg * 4;
#pragma unroll
      for (int j = 0; j < 4; j++)
        sum += ((word >> (bp + j)) & 1u) ? __expf(s4[j]) : 0.f;
    }
  }
  sum += __shfl_xor(sum, 16, 64);
  sum += __shfl_xor(sum, 32, 64);
  if (l < 16) SIo[((size_t)bh << 11) + qr + lr] = 1.0f / sum;
}

// ---------------- kernel B: normalize + attn store + PV ---------------------
// 64 KB LDS -> 2 blocks/CU. attn f32x4 stores issued directly from the exp
// registers (no LDS readback); P written as f16x4 to wave-private swizzled
// LDS for the PV A-fragments.
__global__ __launch_bounds__(512, 4) void attn_pv(const f16* __restrict__ Qh,
                                                  const f16* __restrict__ Kh,
                                                  const f16* __restrict__ VhT,
                                                  const unsigned* __restrict__ mbits,
                                                  const float* __restrict__ SIo,
                                                  float* __restrict__ attn,
                                                  float* __restrict__ ctx) {
  __shared__ f16 lK[8][128][8];     // 16 KB
  __shared__ f16 lVT[16][64][8];    // 16 KB
  __shared__ __align__(16) char Pw[8][4096];  // 32 KB: per-wave P [16][128] f16 swz
  const int wg = blockIdx.x;
  const int bh = ((wg & 7) << 2) | (wg >> 7);
  const int qg = (wg >> 3) & 15;
  const int b = bh >> 4, h = bh & 15;
  const int t = threadIdx.x, w = t >> 6, l = t & 63;
  const int lr = l & 15, lg = l >> 4;
  const int qr = qg * 128 + w * 16;
  char* wb = Pw[w];

  const int pA = t * 16, pB = 8192 + t * 16;
  const int ksA = pA >> 11, rwA = (pA >> 4) & 127;
  const int ksB = pB >> 11, rwB = (pB >> 4) & 127;
  const int vsA = pA >> 10, vdA = (pA >> 4) & 63;
  const int vsB = pB >> 10, vdB = (pB >> 4) & 63;
  const f16* Kbase = Kh + ((size_t)bh << 17);
  const f16* Vbase = VhT + ((size_t)bh << 17);

  const f16* qp = Qh + (((size_t)bh * 2048 + qr + lr) << 6) + lg * 8;
  const f16x8 aq0 = *(const f16x8*)qp;
  const f16x8 aq1 = *(const f16x8*)(qp + 32);
  const unsigned* mrow = mbits + ((size_t)b * 2048 + qr + lr) * 64;
  const float SIq = SIo[((size_t)bh << 11) + qr + lr];
  float* arow = attn + (((size_t)bh * 2048 + qr + lr) << 11);

  f32x4 acc[4] = {};
  f16x8 kra = *(const f16x8*)(Kbase + ((size_t)rwA << 6) + ksA * 8);
  f16x8 krb = *(const f16x8*)(Kbase + ((size_t)rwB << 6) + ksB * 8);
  f16x8 vra = *(const f16x8*)(Vbase + ((size_t)vdA << 11) + vsA * 8);
  f16x8 vrb = *(const f16x8*)(Vbase + ((size_t)vdB << 11) + vsB * 8);
  const int pswz = (lr & 7) << 4;

  for (int t16 = 0; t16 < 16; t16++) {
    const int kb = t16 * 128;
    BAR_LDS();                                // prev-tile LDS readers done
    *(f16x8*)((char*)lK + pA) = kra;
    *(f16x8*)((char*)lK + pB) = krb;
    *(f16x8*)((char*)lVT + pA) = vra;
    *(f16x8*)((char*)lVT + pB) = vrb;
    BAR_LDS();                                // tile ready (no vmcnt drain)
    const uint4 mw4 = *(const uint4*)(mrow + (kb >> 5));
    const unsigned mwv[4] = {mw4.x, mw4.y, mw4.z, mw4.w};
    if (t16 < 15) {
      const f16* nk = Kbase + ((size_t)(kb + 128) << 6);
      kra = *(const f16x8*)(nk + ((size_t)rwA << 6) + ksA * 8);
      krb = *(const f16x8*)(nk + ((size_t)rwB << 6) + ksB * 8);
      const f16* nv = Vbase + kb + 128;
      vra = *(const f16x8*)(nv + ((size_t)vdA << 11) + vsA * 8);
      vrb = *(const f16x8*)(nv + ((size_t)vdB << 11) + vsB * 8);
    }
    // QK^T swapped: lane -> q=lr, keys kb + nf*16 + lg*4 + j (consecutive)
#pragma unroll
    for (int nf = 0; nf < 8; nf++) {
      f32x4 s4 = {};
      s4 = __builtin_amdgcn_mfma_f32_16x16x32_f16(*(const f16x8*)&lK[lg][nf * 16 + lr][0], aq0, s4, 0, 0, 0);
      s4 = __builtin_amdgcn_mfma_f32_16x16x32_f16(*(const f16x8*)&lK[4 + lg][nf * 16 + lr][0], aq1, s4, 0, 0, 0);
      const unsigned word = mwv[nf >> 1];
      const unsigned bp = ((nf & 1) << 4) + lg * 4;
      f32x4 po; f16x4 ph;
#pragma unroll
      for (int j = 0; j < 4; j++) {
        const float pj = ((word >> (bp + j)) & 1u) ? __expf(s4[j]) * SIq : 0.f;
        po[j] = pj; ph[j] = (f16)pj;
      }
      *(f32x4*)(arow + kb + nf * 16 + lg * 4) = po;               // direct attn store
      *(f16x4*)(wb + lr * 256 + ((nf * 32 + lg * 8) ^ pswz)) = ph; // P for PV
    }
    // PV: A = P (wave-private, swizzled), B = V^T tile
#pragma unroll
    for (int kk = 0; kk < 4; kk++) {
      const f16x8 pa = *(const f16x8*)(wb + lr * 256 + ((kk * 64 + lg * 16) ^ pswz));
#pragma unroll
      for (int nf = 0; nf < 4; nf++)
        acc[nf] = __builtin_amdgcn_mfma_f32_16x16x32_f16(pa, *(const f16x8*)&lVT[kk * 4 + lg][nf * 16 + lr][0], acc[nf], 0, 0, 0);
    }
  }

  // ctx write: rows qr+lg*4+j, cols h*64 + nf*16+lr
#pragma unroll
  for (int nf = 0; nf < 4; nf++)
#pragma unroll
    for (int j = 0; j < 4; j++)
      ctx[((size_t)b * 2048 + qr + lg * 4 + j) * 1024 + h * 64 + nf * 16 + lr] = acc[nf][j];
}

// ---------------- residual + LayerNorm (in place on d_out) ------------------
__global__ __launch_bounds__(256) void ln_res(const float* __restrict__ qres,
                                              const float* __restrict__ gamma,
                                              const float* __restrict__ beta,
                                              float* __restrict__ io) {
  const int tok = blockIdx.x;
  const int t = threadIdx.x;
  float* rowp = io + (size_t)tok * 1024;
  const float* qp = qres + (size_t)tok * 1024;
  const f32x4 c = *(const f32x4*)(rowp + t * 4);
  const f32x4 r = *(const f32x4*)(qp + t * 4);
  f32x4 vals;
  float s = 0.f, s2 = 0.f;
#pragma unroll
  for (int e = 0; e < 4; e++) { float x = c[e] + r[e]; vals[e] = x; s += x; s2 += x * x; }
#pragma unroll
  for (int o = 1; o < 64; o <<= 1) { s += __shfl_xor(s, o, 64); s2 += __shfl_xor(s2, o, 64); }
  __shared__ float rs[4][2];
  const int w = t >> 6;
  if ((t & 63) == 0) { rs[w][0] = s; rs[w][1] = s2; }
  __syncthreads();
  s  = rs[0][0] + rs[1][0] + rs[2][0] + rs[3][0];
  s2 = rs[0][1] + rs[1][1] + rs[2][1] + rs[3][1];
  const float mu = s * (1.f / 1024.f);
  const float var = s2 * (1.f / 1024.f) - mu * mu;
  const float rstd = rsqrtf(var + 1e-6f);
  const f32x4 g  = *(const f32x4*)(gamma + t * 4);
  const f32x4 be = *(const f32x4*)(beta + t * 4);
  f32x4 o;
#pragma unroll
  for (int e = 0; e < 4; e++) o[e] = (vals[e] - mu) * rstd * g[e] + be[e];
  *(f32x4*)(rowp + t * 4) = o;
}

// ---------------- host ------------------------------------------------------
extern "C" void kernel_launch(void* const* d_in, const int* in_sizes, int n_in,
                              void* d_out, int out_size, void* d_ws, size_t ws_size,
                              hipStream_t stream) {
  const float* q     = (const float*)d_in[0];
  const float* k     = (const float*)d_in[1];
  const float* v     = (const float*)d_in[2];
  const int*   mask  = (const int*)d_in[3];
  const float* Wq    = (const float*)d_in[4];
  const float* Wk    = (const float*)d_in[5];
  const float* Wv    = (const float*)d_in[6];
  const float* gamma = (const float*)d_in[7];
  const float* beta  = (const float*)d_in[8];
  float* out  = (float*)d_out;
  float* attn = out + (size_t)4194304;       // B*S*H
  const size_t MB = 1u << 20;
  char* ws = (char*)d_ws;

  f16 *x16, *W16, *Qh, *Kh, *Vn, *VhT; unsigned* mb; float* SIo;
  if (ws_size >= 65 * MB) {
    x16 = (f16*)ws;              W16 = (f16*)(ws + 24 * MB);
    Qh  = (f16*)(ws + 30 * MB);  Kh  = (f16*)(ws + 38 * MB);
    Vn  = (f16*)(ws + 46 * MB);  VhT = (f16*)(ws + 54 * MB);
    mb  = (unsigned*)(ws + 62 * MB);
    SIo = (float*)(ws + 63 * MB);
  } else {
    // stage f16 inputs + Vn in the (not-yet-written) attn region of d_out
    x16 = (f16*)attn;            W16 = (f16*)((char*)attn + 24 * MB);
    Vn  = (f16*)((char*)attn + 30 * MB);
    Qh  = (f16*)ws;              Kh  = (f16*)(ws + 8 * MB);
    VhT = (f16*)(ws + 16 * MB);  mb  = (unsigned*)(ws + 24 * MB);
    SIo = (float*)(ws + 25 * MB);
  }

  cvt3<<<dim3(4096, 3), 256, 0, stream>>>(q, k, v, x16, 4194304);
  cvt3<<<dim3(1024, 3), 256, 0, stream>>>(Wq, Wk, Wv, W16, 1048576);
  pack_mask<<<dim3(32768), 256, 0, stream>>>(mask, mb);
  gemm_proj<<<dim3(8, 32, 3), 256, 0, stream>>>(x16, W16, Qh, Kh, Vn);
  transposeV<<<dim3(32, 32), 512, 0, stream>>>(Vn, VhT);
  sumexp_k<<<dim3(512), 512, 0, stream>>>(Qh, Kh, mb, SIo);
  attn_pv<<<dim3(512), 512, 0, stream>>>(Qh, Kh, VhT, mb, SIo, attn, out);
  ln_res<<<dim3(4096), 256, 0, stream>>>(q, gamma, beta, out);
}